// Round 1
// baseline (57.125 us; speedup 1.0000x reference)
//
#include <hip/hip_runtime.h>

// SpikingLinear: 40-step LIF scan over sparse one-shot input spikes.
// Strategy: per-batch stable counting-sort of input indices by spike step,
// transposed weight for coalesced lane-over-o reads, per-wave LIF dynamics in
// registers with early exit once all 256 neurons of the wave have spiked.
//
// Workspace layout (needs ~19.2 MB):
//   [0, 16.78MB)  WT: (IN_DIM+1) x OUT_DIM f32  (row IN_DIM = zero sentinel row)
//   [+0, 2.36MB)  ord: BATCH x ORD_STRIDE int   (byte row-offsets, bucket-sorted)
//   [+0, 42KB)    offs: BATCH x (STEPS+1) int   (padded bucket prefix offsets)

#define IN_DIM     2048
#define OUT_DIM    2048
#define BATCH      256
#define STEPS      40
#define NSLICE     8          // o-slices of 256 -> 2MB WT slice per XCD L2
#define ORD_STRIDE 2304       // 2048 + 40*3 (pad) rounded up, 16B-aligned rows

// ---------------- transpose W[O][IN] -> WT[IN][O] ----------------
__global__ __launch_bounds__(256) void transpose_k(const float* __restrict__ W,
                                                   float* __restrict__ WT) {
    __shared__ float tile[64][65];
    const int bx = blockIdx.x;        // input-dim (j) tile
    const int by = blockIdx.y;        // output-dim (o) tile
    const int x  = threadIdx.x & 63;
    const int y4 = threadIdx.x >> 6;  // 0..3
#pragma unroll
    for (int i = 0; i < 16; ++i) {
        const int a = y4 * 16 + i;    // o-local
        tile[a][x] = W[(size_t)(by * 64 + a) * IN_DIM + (bx * 64 + x)];
    }
    __syncthreads();
#pragma unroll
    for (int i = 0; i < 16; ++i) {
        const int r = y4 * 16 + i;    // j-local
        WT[(size_t)(bx * 64 + r) * OUT_DIM + (by * 64 + x)] = tile[x][r];
    }
}

// ---------------- deterministic stable counting sort per batch ----------------
__global__ __launch_bounds__(256) void sort_k(const float* __restrict__ inp,
                                              int* __restrict__ ord,
                                              int* __restrict__ offs) {
    __shared__ int hist[256 * STEPS];   // per-thread private histograms (40KB)
    __shared__ int tot[STEPS];
    __shared__ int binstart[STEPS + 1];
    const int b = blockIdx.x, t = threadIdx.x;
    for (int i = t; i < 256 * STEPS; i += 256) hist[i] = 0;
    __syncthreads();
    int ks[8];
#pragma unroll
    for (int i = 0; i < 8; ++i) {
        const float v = inp[b * IN_DIM + t * 8 + i];   // = step * 0.5, exact
        const int k = (int)(v * 2.0f);                 // exact integer in fp32
        ks[i] = k;
        ++hist[t * STEPS + k];
    }
    __syncthreads();
    // exclusive prefix over threads, per bin (stable order = ascending j)
    if (t < STEPS) {
        int run = 0;
        for (int tt = 0; tt < 256; ++tt) {
            const int c = hist[tt * STEPS + t];
            hist[tt * STEPS + t] = run;
            run += c;
        }
        tot[t] = run;
    }
    __syncthreads();
    if (t == 0) {
        int run = 0;
        for (int k = 0; k < STEPS; ++k) {
            binstart[k] = run;
            run += (tot[k] + 3) & ~3;   // pad each bucket to multiple of 4
        }
        binstart[STEPS] = run;
    }
    __syncthreads();
    if (t <= STEPS) offs[b * (STEPS + 1) + t] = binstart[t];
    // scatter real entries (premultiplied byte row offsets)
#pragma unroll
    for (int i = 0; i < 8; ++i) {
        const int k = ks[i];
        const int pos = binstart[k] + hist[t * STEPS + k]++;
        ord[b * ORD_STRIDE + pos] = (t * 8 + i) * (OUT_DIM * 4);
    }
    // sentinel padding -> zero row (row index IN_DIM); adding 0.0f is exact
    if (t < STEPS) {
        const int beg = binstart[t] + tot[t];
        const int end = binstart[t] + ((tot[t] + 3) & ~3);
        for (int p = beg; p < end; ++p)
            ord[b * ORD_STRIDE + p] = IN_DIM * (OUT_DIM * 4);
    }
}

// ---------------- main LIF kernel: one wave per (batch, o-slice) ----------------
__global__ __launch_bounds__(64) void snn_k(const float* __restrict__ WT,
                                            const int* __restrict__ ord,
                                            const int* __restrict__ offs,
                                            float* __restrict__ out) {
    const int wid  = blockIdx.x;
    const int s    = wid & (NSLICE - 1);   // slice -> XCD (round-robin dispatch)
    const int b    = wid >> 3;
    const int lane = threadIdx.x;
    const char* wbase = (const char*)WT + ((s * 256 + lane * 4) << 2);
    const int* __restrict__ ob  = ord  + b * ORD_STRIDE;
    const int* __restrict__ off = offs + b * (STEPS + 1);

    float I0 = 0.f, I1 = 0.f, I2 = 0.f, I3 = 0.f;
    float V0 = 0.f, V1 = 0.f, V2 = 0.f, V3 = 0.f;
    int   f0 = 0,   f1 = 0,   f2 = 0,   f3 = 0;
    int p = 0;
    for (int k = 0; k < STEPS; ++k) {
        const int e = off[k + 1];
        float a0 = 0.f, a1 = 0.f, a2 = 0.f, a3 = 0.f;
        for (; p < e; p += 4) {
            const int4 jj = *(const int4*)(ob + p);          // uniform -> s_load
            const float4 w0 = *(const float4*)(wbase + jj.x);
            const float4 w1 = *(const float4*)(wbase + jj.y);
            const float4 w2 = *(const float4*)(wbase + jj.z);
            const float4 w3 = *(const float4*)(wbase + jj.w);
            a0 += w0.x; a1 += w0.y; a2 += w0.z; a3 += w0.w;
            a0 += w1.x; a1 += w1.y; a2 += w1.z; a3 += w1.w;
            a0 += w2.x; a1 += w2.y; a2 += w2.z; a3 += w2.w;
            a0 += w3.x; a1 += w3.y; a2 += w3.z; a3 += w3.w;
        }
        // V uses I from previous step, then I update, then spike check (ref order)
        V0 += 0.025f * (I0 - V0);
        V1 += 0.025f * (I1 - V1);
        V2 += 0.025f * (I2 - V2);
        V3 += 0.025f * (I3 - V3);
        I0 = 0.9f * I0 + a0;
        I1 = 0.9f * I1 + a1;
        I2 = 0.9f * I2 + a2;
        I3 = 0.9f * I3 + a3;
        if (V0 > 1.0f) { if (f0 == 0) f0 = k; V0 = 0.f; }
        if (V1 > 1.0f) { if (f1 == 0) f1 = k; V1 = 0.f; }
        if (V2 > 1.0f) { if (f2 == 0) f2 = k; V2 = 0.f; }
        if (V3 > 1.0f) { if (f3 == 0) f3 = k; V3 = 0.f; }
        if (__all((f0 != 0) & (f1 != 0) & (f2 != 0) & (f3 != 0))) break;
    }
    float4 r;
    r.x = f0 ? (float)f0 : 20.0f;
    r.y = f1 ? (float)f1 : 20.0f;
    r.z = f2 ? (float)f2 : 20.0f;
    r.w = f3 ? (float)f3 : 20.0f;
    *(float4*)(out + (size_t)b * OUT_DIM + s * 256 + lane * 4) = r;
}

extern "C" void kernel_launch(void* const* d_in, const int* in_sizes, int n_in,
                              void* d_out, int out_size, void* d_ws, size_t ws_size,
                              hipStream_t stream) {
    const float* inp = (const float*)d_in[0];
    const float* W   = (const float*)d_in[1];
    float* out = (float*)d_out;
    char*  ws  = (char*)d_ws;

    float* WT = (float*)ws;                                   // (IN_DIM+1) rows
    const size_t WT_BYTES = (size_t)(IN_DIM + 1) * OUT_DIM * sizeof(float);
    int* ord  = (int*)(ws + WT_BYTES);
    int* offs = (int*)(ws + WT_BYTES + (size_t)BATCH * ORD_STRIDE * sizeof(int));

    // zero sentinel row (row IN_DIM of WT)
    hipMemsetAsync(WT + (size_t)IN_DIM * OUT_DIM, 0, OUT_DIM * sizeof(float), stream);
    transpose_k<<<dim3(IN_DIM / 64, OUT_DIM / 64), 256, 0, stream>>>(W, WT);
    sort_k<<<BATCH, 256, 0, stream>>>(inp, ord, offs);
    snn_k<<<BATCH * NSLICE, 64, 0, stream>>>(WT, ord, offs, out);
}

// Round 2
// 52.490 us; speedup vs baseline: 1.0883x; 1.0883x over previous
//
#include <hip/hip_runtime.h>

// SpikingLinear: 40-step LIF scan over sparse one-shot input spikes.
// Strategy: per-batch stable counting-sort of input indices by spike step,
// transposed weight for coalesced lane-over-o reads, per-wave LIF dynamics in
// registers with early exit once all 256 neurons of the wave have spiked.
//
// R2: removed hipMemsetAsync (the runtime fillBuffer kernel cost 41 us per
// replay!) -- sentinel-row zeroing is folded into transpose_k's bx==0 blocks.
//
// Workspace layout (needs ~19.2 MB):
//   [0, 16.78MB)  WT: (IN_DIM+1) x OUT_DIM f32  (row IN_DIM = zero sentinel row)
//   [+0, 2.36MB)  ord: BATCH x ORD_STRIDE int   (byte row-offsets, bucket-sorted)
//   [+0, 42KB)    offs: BATCH x (STEPS+1) int   (padded bucket prefix offsets)

#define IN_DIM     2048
#define OUT_DIM    2048
#define BATCH      256
#define STEPS      40
#define NSLICE     8          // o-slices of 256 -> 2MB WT slice per XCD L2
#define ORD_STRIDE 2304       // 2048 + 40*3 (pad) rounded up, 16B-aligned rows

// ---------------- transpose W[O][IN] -> WT[IN][O] (+ zero sentinel row) ------
__global__ __launch_bounds__(256) void transpose_k(const float* __restrict__ W,
                                                   float* __restrict__ WT) {
    __shared__ float tile[64][65];
    const int bx = blockIdx.x;        // input-dim (j) tile
    const int by = blockIdx.y;        // output-dim (o) tile
    const int x  = threadIdx.x & 63;
    const int y4 = threadIdx.x >> 6;  // 0..3
#pragma unroll
    for (int i = 0; i < 16; ++i) {
        const int a = y4 * 16 + i;    // o-local
        tile[a][x] = W[(size_t)(by * 64 + a) * IN_DIM + (bx * 64 + x)];
    }
    // zero the sentinel row (row IN_DIM) -- one block column does it
    if (bx == 0 && y4 == 0)
        WT[(size_t)IN_DIM * OUT_DIM + by * 64 + x] = 0.0f;
    __syncthreads();
#pragma unroll
    for (int i = 0; i < 16; ++i) {
        const int r = y4 * 16 + i;    // j-local
        WT[(size_t)(bx * 64 + r) * OUT_DIM + (by * 64 + x)] = tile[x][r];
    }
}

// ---------------- deterministic stable counting sort per batch ----------------
__global__ __launch_bounds__(256) void sort_k(const float* __restrict__ inp,
                                              int* __restrict__ ord,
                                              int* __restrict__ offs) {
    __shared__ int hist[256 * STEPS];   // per-thread private histograms (40KB)
    __shared__ int tot[STEPS];
    __shared__ int binstart[STEPS + 1];
    const int b = blockIdx.x, t = threadIdx.x;
    for (int i = t; i < 256 * STEPS; i += 256) hist[i] = 0;
    __syncthreads();
    int ks[8];
#pragma unroll
    for (int i = 0; i < 8; ++i) {
        const float v = inp[b * IN_DIM + t * 8 + i];   // = step * 0.5, exact
        const int k = (int)(v * 2.0f);                 // exact integer in fp32
        ks[i] = k;
        ++hist[t * STEPS + k];
    }
    __syncthreads();
    // exclusive prefix over threads, per bin (stable order = ascending j)
    if (t < STEPS) {
        int run = 0;
        for (int tt = 0; tt < 256; ++tt) {
            const int c = hist[tt * STEPS + t];
            hist[tt * STEPS + t] = run;
            run += c;
        }
        tot[t] = run;
    }
    __syncthreads();
    if (t == 0) {
        int run = 0;
        for (int k = 0; k < STEPS; ++k) {
            binstart[k] = run;
            run += (tot[k] + 3) & ~3;   // pad each bucket to multiple of 4
        }
        binstart[STEPS] = run;
    }
    __syncthreads();
    if (t <= STEPS) offs[b * (STEPS + 1) + t] = binstart[t];
    // scatter real entries (premultiplied byte row offsets)
#pragma unroll
    for (int i = 0; i < 8; ++i) {
        const int k = ks[i];
        const int pos = binstart[k] + hist[t * STEPS + k]++;
        ord[b * ORD_STRIDE + pos] = (t * 8 + i) * (OUT_DIM * 4);
    }
    // sentinel padding -> zero row (row index IN_DIM); adding 0.0f is exact
    if (t < STEPS) {
        const int beg = binstart[t] + tot[t];
        const int end = binstart[t] + ((tot[t] + 3) & ~3);
        for (int p = beg; p < end; ++p)
            ord[b * ORD_STRIDE + p] = IN_DIM * (OUT_DIM * 4);
    }
}

// ---------------- main LIF kernel: one wave per (batch, o-slice) ----------------
__global__ __launch_bounds__(64) void snn_k(const float* __restrict__ WT,
                                            const int* __restrict__ ord,
                                            const int* __restrict__ offs,
                                            float* __restrict__ out) {
    const int wid  = blockIdx.x;
    const int s    = wid & (NSLICE - 1);   // slice -> XCD (round-robin dispatch)
    const int b    = wid >> 3;
    const int lane = threadIdx.x;
    const char* wbase = (const char*)WT + ((s * 256 + lane * 4) << 2);
    const int* __restrict__ ob  = ord  + b * ORD_STRIDE;
    const int* __restrict__ off = offs + b * (STEPS + 1);

    float I0 = 0.f, I1 = 0.f, I2 = 0.f, I3 = 0.f;
    float V0 = 0.f, V1 = 0.f, V2 = 0.f, V3 = 0.f;
    int   f0 = 0,   f1 = 0,   f2 = 0,   f3 = 0;
    int p = 0;
    for (int k = 0; k < STEPS; ++k) {
        const int e = off[k + 1];
        float a0 = 0.f, a1 = 0.f, a2 = 0.f, a3 = 0.f;
        for (; p < e; p += 4) {
            const int4 jj = *(const int4*)(ob + p);          // uniform, coalesced
            const float4 w0 = *(const float4*)(wbase + jj.x);
            const float4 w1 = *(const float4*)(wbase + jj.y);
            const float4 w2 = *(const float4*)(wbase + jj.z);
            const float4 w3 = *(const float4*)(wbase + jj.w);
            a0 += w0.x; a1 += w0.y; a2 += w0.z; a3 += w0.w;
            a0 += w1.x; a1 += w1.y; a2 += w1.z; a3 += w1.w;
            a0 += w2.x; a1 += w2.y; a2 += w2.z; a3 += w2.w;
            a0 += w3.x; a1 += w3.y; a2 += w3.z; a3 += w3.w;
        }
        // V uses I from previous step, then I update, then spike check (ref order)
        V0 += 0.025f * (I0 - V0);
        V1 += 0.025f * (I1 - V1);
        V2 += 0.025f * (I2 - V2);
        V3 += 0.025f * (I3 - V3);
        I0 = 0.9f * I0 + a0;
        I1 = 0.9f * I1 + a1;
        I2 = 0.9f * I2 + a2;
        I3 = 0.9f * I3 + a3;
        if (V0 > 1.0f) { if (f0 == 0) f0 = k; V0 = 0.f; }
        if (V1 > 1.0f) { if (f1 == 0) f1 = k; V1 = 0.f; }
        if (V2 > 1.0f) { if (f2 == 0) f2 = k; V2 = 0.f; }
        if (V3 > 1.0f) { if (f3 == 0) f3 = k; V3 = 0.f; }
        if (__all((f0 != 0) & (f1 != 0) & (f2 != 0) & (f3 != 0))) break;
    }
    float4 r;
    r.x = f0 ? (float)f0 : 20.0f;
    r.y = f1 ? (float)f1 : 20.0f;
    r.z = f2 ? (float)f2 : 20.0f;
    r.w = f3 ? (float)f3 : 20.0f;
    *(float4*)(out + (size_t)b * OUT_DIM + s * 256 + lane * 4) = r;
}

extern "C" void kernel_launch(void* const* d_in, const int* in_sizes, int n_in,
                              void* d_out, int out_size, void* d_ws, size_t ws_size,
                              hipStream_t stream) {
    const float* inp = (const float*)d_in[0];
    const float* W   = (const float*)d_in[1];
    float* out = (float*)d_out;
    char*  ws  = (char*)d_ws;

    float* WT = (float*)ws;                                   // (IN_DIM+1) rows
    const size_t WT_BYTES = (size_t)(IN_DIM + 1) * OUT_DIM * sizeof(float);
    int* ord  = (int*)(ws + WT_BYTES);
    int* offs = (int*)(ws + WT_BYTES + (size_t)BATCH * ORD_STRIDE * sizeof(int));

    transpose_k<<<dim3(IN_DIM / 64, OUT_DIM / 64), 256, 0, stream>>>(W, WT);
    sort_k<<<BATCH, 256, 0, stream>>>(inp, ord, offs);
    snn_k<<<BATCH * NSLICE, 64, 0, stream>>>(WT, ord, offs, out);
}